// Round 2
// baseline (707.682 us; speedup 1.0000x reference)
//
#include <hip/hip_runtime.h>

#define DI __device__ __forceinline__

constexpr int AEV = 384;
constexpr int H1N = 160;
constexpr int H2N = 128;
constexpr int H3N = 96;
constexpr int NSP = 4;
constexpr int TM  = 128;   // atoms per block
constexpr int SP1 = 168;   // H1 row stride (shorts; 84 words mod 32 = 20 -> 2-way, free)
constexpr int SP2 = 136;   // H2 row stride (68 words mod 32 = 4 -> 2-way, free)
constexpr int SP3 = 104;   // H3 row stride (52 words mod 32 = 20 -> 2-way, free)

using short8  = __attribute__((ext_vector_type(8))) short;
using short4v = __attribute__((ext_vector_type(4))) short;
using f32x4   = __attribute__((ext_vector_type(4))) float;

// Pre-transposed bf16 hi/lo weight copies, [species][neuron][k] — L2-resident (~2.9 MB)
__device__ __align__(16) short g_w1h[NSP * H1N * AEV];
__device__ __align__(16) short g_w1l[NSP * H1N * AEV];
__device__ __align__(16) short g_w2h[NSP * H2N * H1N];
__device__ __align__(16) short g_w2l[NSP * H2N * H1N];
__device__ __align__(16) short g_w3h[NSP * H3N * H2N];
__device__ __align__(16) short g_w3l[NSP * H3N * H2N];

DI short f2bf(float f) {                       // RTE fp32 -> bf16
  unsigned u = __float_as_uint(f);
  u += 0x7fffu + ((u >> 16) & 1u);
  return (short)(u >> 16);
}
DI float bf2f(short h) {
  return __uint_as_float(((unsigned)(unsigned short)h) << 16);
}
DI float celu_f(float x) {                     // celu(x,0.1) = max(x,0)+0.1*(exp(min(x,0)/0.1)-1)
  return fmaxf(x, 0.f) + 0.1f * (exp2f(fminf(x, 0.f) * 14.426950408889634f) - 1.f);
}
DI f32x4 mfma16(short8 a, short8 b, f32x4 c) {
  return __builtin_amdgcn_mfma_f32_16x16x32_bf16(a, b, c, 0, 0, 0);
}

// ---------------- prologue: transpose + hi/lo split, fused for all 3 layers ----
template <int K, int N>
DI void tp(const float* __restrict__ src, short* dh, short* dl, int id) {
  constexpr int per = K * N;
  int s = id / per, r = id % per;
  int n = r / K, k = r % K;            // consecutive id -> consecutive k -> coalesced writes
  float v = src[s * per + k * N + n];
  short h = f2bf(v);
  dh[s * per + n * K + k] = h;
  dl[s * per + n * K + k] = f2bf(v - bf2f(h));
}

__global__ void prep(const float* __restrict__ W1, const float* __restrict__ W2,
                     const float* __restrict__ W3, float* __restrict__ out) {
  int id = blockIdx.x * 256 + threadIdx.x;
  if (id == 0) out[0] = 0.f;
  constexpr int E1 = NSP * AEV * H1N;   // 245760
  constexpr int E2 = NSP * H1N * H2N;   //  81920
  constexpr int E3 = NSP * H2N * H3N;   //  49152
  if (id < E1)            tp<AEV, H1N>(W1, g_w1h, g_w1l, id);
  else if (id < E1 + E2)  tp<H1N, H2N>(W2, g_w2h, g_w2l, id - E1);
  else if (id < E1 + E2 + E3) tp<H2N, H3N>(W3, g_w3h, g_w3l, id - E1 - E2);
}

// ---------------- layers 2/3: B from LDS, A direct from global (L1/L2-hit) ----
template <int MT, int K>
DI void layer_lds(const short* __restrict__ wtH, const short* __restrict__ wtL,
                  const short* Hsrc, int SPs, short* Hdst, int SPd,
                  const float* __restrict__ biasG,
                  int l15, int quad, int wav) {
  constexpr int NKS = K / 32;
  f32x4 acc[MT][2];
#pragma unroll
  for (int m = 0; m < MT; ++m)
#pragma unroll
    for (int nt = 0; nt < 2; ++nt)
#pragma unroll
      for (int i = 0; i < 4; ++i) acc[m][nt][i] = 0.f;

  short8 b[NKS][2];
#pragma unroll
  for (int ks = 0; ks < NKS; ++ks)
#pragma unroll
    for (int nt = 0; nt < 2; ++nt)
      b[ks][nt] = *(const short8*)(Hsrc + (wav * 32 + nt * 16 + l15) * SPs + ks * 32 + quad * 8);

#pragma unroll
  for (int mt = 0; mt < MT; ++mt) {
    const short* ph = wtH + (mt * 16 + l15) * K + quad * 8;
    const short* pl = wtL + (mt * 16 + l15) * K + quad * 8;
#pragma unroll
    for (int ks = 0; ks < NKS; ++ks) {
      short8 ah = *(const short8*)(ph + ks * 32);
      short8 al = *(const short8*)(pl + ks * 32);
#pragma unroll
      for (int nt = 0; nt < 2; ++nt) {
        acc[mt][nt] = mfma16(ah, b[ks][nt], acc[mt][nt]);
        acc[mt][nt] = mfma16(al, b[ks][nt], acc[mt][nt]);
      }
    }
  }
  // bias + celu + bf16; D C-layout (col=atom=l15, rows=quad*4+j) -> row-major [atom][neuron]
#pragma unroll
  for (int mt = 0; mt < MT; ++mt) {
    float4 bb = *(const float4*)(biasG + mt * 16 + quad * 4);
#pragma unroll
    for (int nt = 0; nt < 2; ++nt) {
      int atom = wav * 32 + nt * 16 + l15;
      short4v o;
      o[0] = f2bf(celu_f(acc[mt][nt][0] + bb.x));
      o[1] = f2bf(celu_f(acc[mt][nt][1] + bb.y));
      o[2] = f2bf(celu_f(acc[mt][nt][2] + bb.z));
      o[3] = f2bf(celu_f(acc[mt][nt][3] + bb.w));
      *(short4v*)(Hdst + atom * SPd + mt * 16 + quad * 4) = o;
    }
  }
}

__global__ __launch_bounds__(256, 2) void fused_mlp(
    const float* __restrict__ aev,
    const float* __restrict__ b1, const float* __restrict__ b2,
    const float* __restrict__ b3,
    const float* __restrict__ W4, const float* __restrict__ pb4,
    const int* __restrict__ i0, const int* __restrict__ i1,
    const int* __restrict__ i2, const int* __restrict__ i3,
    int chunk, float* __restrict__ out) {
  __shared__ __align__(16) short H1s[TM * SP1];   // 43008 B (reused as H3, stride SP3)
  __shared__ __align__(16) short H2s[TM * SP2];   // 34816 B          -> total 77.8 KB, 2 blk/CU
  __shared__ float RED[4];

  const int tid  = threadIdx.x;
  const int lane = tid & 63, wav = tid >> 6;
  const int l15  = lane & 15, quad = lane >> 4;   // MFMA 16x16x32 lane decomposition
  const int s    = blockIdx.y;
  const int tile = blockIdx.x;
  const int* idx = (s == 0) ? i0 : (s == 1) ? i1 : (s == 2) ? i2 : i3;

  const short* w1h = g_w1h + s * H1N * AEV; const short* w1l = g_w1l + s * H1N * AEV;
  const short* w2h = g_w2h + s * H2N * H1N; const short* w2l = g_w2l + s * H2N * H1N;
  const short* w3h = g_w3h + s * H3N * H2N; const short* w3l = g_w3l + s * H3N * H2N;

  // per-lane gather rows for its two 16-atom column tiles
  const int a0 = tile * TM + wav * 32 + l15;
  const int a1 = a0 + 16;
  const int r0 = idx[a0 < chunk ? a0 : (chunk - 1)];
  const int r1 = idx[a1 < chunk ? a1 : (chunk - 1)];
  const float* xrow0 = aev + (size_t)r0 * AEV + quad * 8;
  const float* xrow1 = aev + (size_t)r1 * AEV + quad * 8;

  // ---------------- Layer 1: H1^T = celu(W1^T X^T + b1), B gathered from HBM,
  // A (hi/lo bf16) direct from global; gather software-pipelined per 96-k chunk.
  f32x4 acc[10][2];
#pragma unroll
  for (int m = 0; m < 10; ++m)
#pragma unroll
    for (int nt = 0; nt < 2; ++nt)
#pragma unroll
      for (int i = 0; i < 4; ++i) acc[m][nt][i] = 0.f;

  float4 xgf[3][2][2];
  short8 xb[3][2];

  auto ldx = [&](int c) {
#pragma unroll
    for (int ks = 0; ks < 3; ++ks)
#pragma unroll
      for (int nt = 0; nt < 2; ++nt) {
        const float* p = (nt ? xrow1 : xrow0) + c * 96 + ks * 32;
        xgf[ks][nt][0] = *(const float4*)p;
        xgf[ks][nt][1] = *(const float4*)(p + 4);
      }
  };

  ldx(0);
#pragma unroll
  for (int c = 0; c < 4; ++c) {
    // convert current chunk to bf16 B-fragments
#pragma unroll
    for (int ks = 0; ks < 3; ++ks)
#pragma unroll
      for (int nt = 0; nt < 2; ++nt) {
        float4 A = xgf[ks][nt][0], B = xgf[ks][nt][1];
        short8 t;
        t[0] = f2bf(A.x); t[1] = f2bf(A.y); t[2] = f2bf(A.z); t[3] = f2bf(A.w);
        t[4] = f2bf(B.x); t[5] = f2bf(B.y); t[6] = f2bf(B.z); t[7] = f2bf(B.w);
        xb[ks][nt] = t;
      }
    if (c < 3) ldx(c + 1);              // prefetch next chunk's HBM gather
#pragma unroll
    for (int mt = 0; mt < 10; ++mt) {
      const short* ph = w1h + (mt * 16 + l15) * AEV + c * 96 + quad * 8;
      const short* pl = w1l + (mt * 16 + l15) * AEV + c * 96 + quad * 8;
#pragma unroll
      for (int ks = 0; ks < 3; ++ks) {
        short8 ah = *(const short8*)(ph + ks * 32);
        short8 al = *(const short8*)(pl + ks * 32);
#pragma unroll
        for (int nt = 0; nt < 2; ++nt) {
          acc[mt][nt] = mfma16(ah, xb[ks][nt], acc[mt][nt]);
          acc[mt][nt] = mfma16(al, xb[ks][nt], acc[mt][nt]);
        }
      }
    }
  }
#pragma unroll
  for (int mt = 0; mt < 10; ++mt) {
    float4 bb = *(const float4*)(b1 + s * H1N + mt * 16 + quad * 4);
#pragma unroll
    for (int nt = 0; nt < 2; ++nt) {
      int atom = wav * 32 + nt * 16 + l15;
      short4v o;
      o[0] = f2bf(celu_f(acc[mt][nt][0] + bb.x));
      o[1] = f2bf(celu_f(acc[mt][nt][1] + bb.y));
      o[2] = f2bf(celu_f(acc[mt][nt][2] + bb.z));
      o[3] = f2bf(celu_f(acc[mt][nt][3] + bb.w));
      *(short4v*)(H1s + atom * SP1 + mt * 16 + quad * 4) = o;
    }
  }

  // ---------------- Layers 2 and 3 (H3 aliases the H1 buffer)
  __syncthreads();
  layer_lds<8, 160>(w2h, w2l, H1s, SP1, H2s, SP2, b2 + s * H2N, l15, quad, wav);
  __syncthreads();
  layer_lds<6, 128>(w3h, w3l, H2s, SP2, H1s, SP3, b3 + s * H3N, l15, quad, wav);
  __syncthreads();

  // ---------------- Layer 4: per-atom dot(H3, w4) + b4, then block reduce
  float e = 0.f;
  if (tid < TM) {
    const short* h3 = H1s + tid * SP3;
    const float* w4 = W4 + s * H3N;
    float sum = 0.f;
#pragma unroll
    for (int j = 0; j < 12; ++j) {
      short8 h8 = *(const short8*)(h3 + j * 8);
      float4 wa = *(const float4*)(w4 + j * 8);
      float4 wb = *(const float4*)(w4 + j * 8 + 4);
      sum += bf2f(h8[0]) * wa.x + bf2f(h8[1]) * wa.y + bf2f(h8[2]) * wa.z + bf2f(h8[3]) * wa.w
           + bf2f(h8[4]) * wb.x + bf2f(h8[5]) * wb.y + bf2f(h8[6]) * wb.z + bf2f(h8[7]) * wb.w;
    }
    if (tile * TM + tid < chunk) e = sum + pb4[s];
  }
#pragma unroll
  for (int off = 32; off > 0; off >>= 1) e += __shfl_down(e, off, 64);
  if (lane == 0) RED[wav] = e;
  __syncthreads();
  if (tid == 0) atomicAdd(out, RED[0] + RED[1] + RED[2] + RED[3]);
}

extern "C" void kernel_launch(void* const* d_in, const int* in_sizes, int n_in,
                              void* d_out, int out_size, void* d_ws, size_t ws_size,
                              hipStream_t stream) {
  (void)n_in; (void)d_ws; (void)ws_size; (void)out_size;
  const float* aev = (const float*)d_in[0];
  const float* W1  = (const float*)d_in[1];
  const float* b1  = (const float*)d_in[2];
  const float* W2  = (const float*)d_in[3];
  const float* b2  = (const float*)d_in[4];
  const float* W3  = (const float*)d_in[5];
  const float* b3  = (const float*)d_in[6];
  const float* W4  = (const float*)d_in[7];
  const float* b4  = (const float*)d_in[8];
  const int* iH = (const int*)d_in[9];
  const int* iC = (const int*)d_in[10];
  const int* iN = (const int*)d_in[11];
  const int* iO = (const int*)d_in[12];
  const int chunk = in_sizes[9];

  constexpr int TOT = NSP * (AEV * H1N + H1N * H2N + H2N * H3N);  // 376832 = 1472*256
  prep<<<TOT / 256, 256, 0, stream>>>(W1, W2, W3, (float*)d_out);

  const int tiles = (chunk + TM - 1) / TM;
  dim3 grid(tiles, NSP);
  fused_mlp<<<grid, 256, 0, stream>>>(aev, b1, b2, b3, W4, b4,
                                      iH, iC, iN, iO, chunk, (float*)d_out);
}

// Round 3
// 582.554 us; speedup vs baseline: 1.2148x; 1.2148x over previous
//
#include <hip/hip_runtime.h>

#define DI __device__ __forceinline__

constexpr int AEV = 384;
constexpr int H1N = 160;
constexpr int H2N = 128;
constexpr int H3N = 96;
constexpr int NSP = 4;
constexpr int TM  = 128;   // atoms per block (4 waves x 32)
constexpr int SP1 = 168;   // H1 row stride in halfs (+8 pad; 84 words %32=20 -> <=2-way)
constexpr int SP2 = 136;   // H2 row stride (68 words %32=4 -> <=2-way)
constexpr int SP3 = 104;   // H3 row stride (52 words %32=20 -> <=2-way)

using half8  = __attribute__((ext_vector_type(8))) _Float16;
using half4v = __attribute__((ext_vector_type(4))) _Float16;
using f32x4  = __attribute__((ext_vector_type(4))) float;

// Pre-transposed fp16 weights, [species][neuron][k] — 753 KB total, L2-resident everywhere
__device__ __align__(16) _Float16 g_w1[NSP * H1N * AEV];
__device__ __align__(16) _Float16 g_w2[NSP * H2N * H1N];
__device__ __align__(16) _Float16 g_w3[NSP * H3N * H2N];

DI float celu_f(float x) {   // celu(x,0.1) = max(x,0)+0.1*(exp(min(x,0)/0.1)-1)
  return fmaxf(x, 0.f) + 0.1f * (exp2f(fminf(x, 0.f) * 14.426950408889634f) - 1.f);
}
DI f32x4 mfma16h(half8 a, half8 b, f32x4 c) {
  return __builtin_amdgcn_mfma_f32_16x16x32_f16(a, b, c, 0, 0, 0);
}
DI half8 cvt8(float4 a, float4 b) {
  half8 t;
  t[0] = (_Float16)a.x; t[1] = (_Float16)a.y; t[2] = (_Float16)a.z; t[3] = (_Float16)a.w;
  t[4] = (_Float16)b.x; t[5] = (_Float16)b.y; t[6] = (_Float16)b.z; t[7] = (_Float16)b.w;
  return t;
}

// ---------------- prologue: transpose to [s][n][k] fp16, fused for 3 layers ----
template <int K, int N>
DI void tp(const float* __restrict__ src, _Float16* dst, int id) {
  constexpr int per = K * N;
  int s = id / per, r = id % per;
  int n = r / K, k = r % K;            // consecutive id -> consecutive k -> coalesced writes
  dst[s * per + n * K + k] = (_Float16)src[s * per + k * N + n];
}

__global__ void prep(const float* __restrict__ W1, const float* __restrict__ W2,
                     const float* __restrict__ W3, float* __restrict__ out) {
  int id = blockIdx.x * 256 + threadIdx.x;
  if (id == 0) out[0] = 0.f;
  constexpr int E1 = NSP * AEV * H1N;   // 245760
  constexpr int E2 = NSP * H1N * H2N;   //  81920
  constexpr int E3 = NSP * H2N * H3N;   //  49152
  if (id < E1)                 tp<AEV, H1N>(W1, g_w1, id);
  else if (id < E1 + E2)       tp<H1N, H2N>(W2, g_w2, id - E1);
  else if (id < E1 + E2 + E3)  tp<H2N, H3N>(W3, g_w3, id - E1 - E2);
}

// ---------------- fused MLP: one wave = 32 atoms end-to-end, no barriers ----
__global__ void __launch_bounds__(256) __attribute__((amdgpu_waves_per_eu(2, 2)))
fused_mlp(const float* __restrict__ aev,
          const float* __restrict__ b1, const float* __restrict__ b2,
          const float* __restrict__ b3,
          const float* __restrict__ W4, const float* __restrict__ pb4,
          const int* __restrict__ i0, const int* __restrict__ i1,
          const int* __restrict__ i2, const int* __restrict__ i3,
          int chunk, float* __restrict__ out) {
  // per-wave private slices: 4 x (32*SP1 + 32*SP2) halfs = 77.8 KB -> 2 blocks/CU
  __shared__ __align__(16) _Float16 HB[4 * 32 * (SP1 + SP2)];
  __shared__ float RED[4];

  const int tid  = threadIdx.x;
  const int lane = tid & 63, wav = tid >> 6;
  const int l15  = lane & 15, quad = lane >> 4;   // MFMA 16x16x32 lane decomposition
  const int s    = blockIdx.y;
  const int* idx = (s == 0) ? i0 : (s == 1) ? i1 : (s == 2) ? i2 : i3;

  _Float16* H1w = HB + wav * (32 * SP1);                 // [atom(0..31)][SP1]
  _Float16* H2w = HB + 4 * (32 * SP1) + wav * (32 * SP2);

  const _Float16* w1 = g_w1 + s * H1N * AEV;
  const _Float16* w2 = g_w2 + s * H2N * H1N;
  const _Float16* w3 = g_w3 + s * H3N * H2N;

  // this wave's 32 atoms
  const int abase = (blockIdx.x * 4 + wav) * 32;
  const int a0 = abase + l15, a1 = a0 + 16;
  const int r0 = idx[a0 < chunk ? a0 : (chunk - 1)];
  const int r1 = idx[a1 < chunk ? a1 : (chunk - 1)];
  const float* xr0 = aev + (size_t)r0 * AEV + quad * 8;
  const float* xr1 = aev + (size_t)r1 * AEV + quad * 8;

  // ---------- Layer 1: D[neuron, atom], A = W1 rows direct from L2, B gathered HBM
  f32x4 acc[10][2];
#pragma unroll
  for (int m = 0; m < 10; ++m)
#pragma unroll
    for (int nt = 0; nt < 2; ++nt)
#pragma unroll
      for (int i = 0; i < 4; ++i) acc[m][nt][i] = 0.f;

  float4 xf00, xf01, xf10, xf11;       // current 32-k slab, fp32
  xf00 = *(const float4*)(xr0); xf01 = *(const float4*)(xr0 + 4);
  xf10 = *(const float4*)(xr1); xf11 = *(const float4*)(xr1 + 4);

#pragma unroll
  for (int ks = 0; ks < 12; ++ks) {
    half8 bv0 = cvt8(xf00, xf01);
    half8 bv1 = cvt8(xf10, xf11);
    if (ks < 11) {                      // prefetch next slab
      xf00 = *(const float4*)(xr0 + (ks + 1) * 32);
      xf01 = *(const float4*)(xr0 + (ks + 1) * 32 + 4);
      xf10 = *(const float4*)(xr1 + (ks + 1) * 32);
      xf11 = *(const float4*)(xr1 + (ks + 1) * 32 + 4);
    }
    const _Float16* pa = w1 + l15 * AEV + ks * 32 + quad * 8;
#pragma unroll
    for (int mt = 0; mt < 10; ++mt) {
      half8 a = *(const half8*)(pa + mt * 16 * AEV);
      acc[mt][0] = mfma16h(a, bv0, acc[mt][0]);
      acc[mt][1] = mfma16h(a, bv1, acc[mt][1]);
    }
  }
  // epilogue: bias+celu+fp16, C-layout (col=atom=l15, rows=quad*4+j) -> [atom][neuron]
#pragma unroll
  for (int mt = 0; mt < 10; ++mt) {
    float4 bb = *(const float4*)(b1 + s * H1N + mt * 16 + quad * 4);
#pragma unroll
    for (int nt = 0; nt < 2; ++nt) {
      int atom = nt * 16 + l15;
      half4v o;
      o[0] = (_Float16)celu_f(acc[mt][nt][0] + bb.x);
      o[1] = (_Float16)celu_f(acc[mt][nt][1] + bb.y);
      o[2] = (_Float16)celu_f(acc[mt][nt][2] + bb.z);
      o[3] = (_Float16)celu_f(acc[mt][nt][3] + bb.w);
      *(half4v*)(H1w + atom * SP1 + mt * 16 + quad * 4) = o;
    }
  }

  // ---------- Layer 2: B from H1w (LDS), A = W2 rows from L2
  {
    f32x4 acc2[8][2];
#pragma unroll
    for (int m = 0; m < 8; ++m)
#pragma unroll
      for (int nt = 0; nt < 2; ++nt)
#pragma unroll
        for (int i = 0; i < 4; ++i) acc2[m][nt][i] = 0.f;
    half8 bb2[5][2];
#pragma unroll
    for (int ks = 0; ks < 5; ++ks)
#pragma unroll
      for (int nt = 0; nt < 2; ++nt)
        bb2[ks][nt] = *(const half8*)(H1w + (nt * 16 + l15) * SP1 + ks * 32 + quad * 8);
#pragma unroll
    for (int mt = 0; mt < 8; ++mt) {
      const _Float16* pa = w2 + (mt * 16 + l15) * H1N + quad * 8;
#pragma unroll
      for (int ks = 0; ks < 5; ++ks) {
        half8 a = *(const half8*)(pa + ks * 32);
        acc2[mt][0] = mfma16h(a, bb2[ks][0], acc2[mt][0]);
        acc2[mt][1] = mfma16h(a, bb2[ks][1], acc2[mt][1]);
      }
    }
#pragma unroll
    for (int mt = 0; mt < 8; ++mt) {
      float4 bb = *(const float4*)(b2 + s * H2N + mt * 16 + quad * 4);
#pragma unroll
      for (int nt = 0; nt < 2; ++nt) {
        int atom = nt * 16 + l15;
        half4v o;
        o[0] = (_Float16)celu_f(acc2[mt][nt][0] + bb.x);
        o[1] = (_Float16)celu_f(acc2[mt][nt][1] + bb.y);
        o[2] = (_Float16)celu_f(acc2[mt][nt][2] + bb.z);
        o[3] = (_Float16)celu_f(acc2[mt][nt][3] + bb.w);
        *(half4v*)(H2w + atom * SP2 + mt * 16 + quad * 4) = o;
      }
    }
  }

  // ---------- Layer 3: B from H2w, A = W3 rows; out -> H1w (stride SP3)
  {
    f32x4 acc3[6][2];
#pragma unroll
    for (int m = 0; m < 6; ++m)
#pragma unroll
      for (int nt = 0; nt < 2; ++nt)
#pragma unroll
        for (int i = 0; i < 4; ++i) acc3[m][nt][i] = 0.f;
    half8 bb3[4][2];
#pragma unroll
    for (int ks = 0; ks < 4; ++ks)
#pragma unroll
      for (int nt = 0; nt < 2; ++nt)
        bb3[ks][nt] = *(const half8*)(H2w + (nt * 16 + l15) * SP2 + ks * 32 + quad * 8);
#pragma unroll
    for (int mt = 0; mt < 6; ++mt) {
      const _Float16* pa = w3 + (mt * 16 + l15) * H2N + quad * 8;
#pragma unroll
      for (int ks = 0; ks < 4; ++ks) {
        half8 a = *(const half8*)(pa + ks * 32);
        acc3[mt][0] = mfma16h(a, bb3[ks][0], acc3[mt][0]);
        acc3[mt][1] = mfma16h(a, bb3[ks][1], acc3[mt][1]);
      }
    }
#pragma unroll
    for (int mt = 0; mt < 6; ++mt) {
      float4 bb = *(const float4*)(b3 + s * H3N + mt * 16 + quad * 4);
#pragma unroll
      for (int nt = 0; nt < 2; ++nt) {
        int atom = nt * 16 + l15;
        half4v o;
        o[0] = (_Float16)celu_f(acc3[mt][nt][0] + bb.x);
        o[1] = (_Float16)celu_f(acc3[mt][nt][1] + bb.y);
        o[2] = (_Float16)celu_f(acc3[mt][nt][2] + bb.z);
        o[3] = (_Float16)celu_f(acc3[mt][nt][3] + bb.w);
        *(half4v*)(H1w + atom * SP3 + mt * 16 + quad * 4) = o;   // H3 aliases H1 slice
      }
    }
  }

  // ---------- Layer 4: 2 lanes per atom, dot(H3, w4)+b4, wave reduce
  {
    const int atom = lane >> 1, h = lane & 1;
    const _Float16* h3 = H1w + atom * SP3 + h * 48;
    const float* w4 = W4 + s * H3N + h * 48;
    float e = 0.f;
#pragma unroll
    for (int j = 0; j < 6; ++j) {
      half8 hv = *(const half8*)(h3 + j * 8);
      float4 wa = *(const float4*)(w4 + j * 8);
      float4 wb = *(const float4*)(w4 + j * 8 + 4);
      e += (float)hv[0] * wa.x + (float)hv[1] * wa.y + (float)hv[2] * wa.z + (float)hv[3] * wa.w
         + (float)hv[4] * wb.x + (float)hv[5] * wb.y + (float)hv[6] * wb.z + (float)hv[7] * wb.w;
    }
    e += __shfl_down(e, 1, 64);                    // even lanes: atom total
    bool valid = (h == 0) && (abase + atom < chunk);
    e = valid ? (e + pb4[s]) : 0.f;
#pragma unroll
    for (int off = 32; off > 0; off >>= 1) e += __shfl_down(e, off, 64);
    if (lane == 0) RED[wav] = e;
  }
  __syncthreads();
  if (tid == 0) atomicAdd(out, RED[0] + RED[1] + RED[2] + RED[3]);
}

extern "C" void kernel_launch(void* const* d_in, const int* in_sizes, int n_in,
                              void* d_out, int out_size, void* d_ws, size_t ws_size,
                              hipStream_t stream) {
  (void)n_in; (void)d_ws; (void)ws_size; (void)out_size;
  const float* aev = (const float*)d_in[0];
  const float* W1  = (const float*)d_in[1];
  const float* b1  = (const float*)d_in[2];
  const float* W2  = (const float*)d_in[3];
  const float* b2  = (const float*)d_in[4];
  const float* W3  = (const float*)d_in[5];
  const float* b3  = (const float*)d_in[6];
  const float* W4  = (const float*)d_in[7];
  const float* b4  = (const float*)d_in[8];
  const int* iH = (const int*)d_in[9];
  const int* iC = (const int*)d_in[10];
  const int* iN = (const int*)d_in[11];
  const int* iO = (const int*)d_in[12];
  const int chunk = in_sizes[9];

  constexpr int TOT = NSP * (AEV * H1N + H1N * H2N + H2N * H3N);  // 376832 = 1472*256
  prep<<<TOT / 256, 256, 0, stream>>>(W1, W2, W3, (float*)d_out);

  const int tiles = (chunk + TM - 1) / TM;
  dim3 grid(tiles, NSP);
  fused_mlp<<<grid, 256, 0, stream>>>(aev, b1, b2, b3, W4, b4,
                                      iH, iC, iN, iO, chunk, (float*)d_out);
}

// Round 4
// 512.066 us; speedup vs baseline: 1.3820x; 1.1377x over previous
//
#include <hip/hip_runtime.h>

#define DI __device__ __forceinline__

constexpr int AEV = 384;
constexpr int H1N = 160;
constexpr int H2N = 128;
constexpr int H3N = 96;
constexpr int NSP = 4;
constexpr int W1P = 392;   // W1 LDS row stride (halfs): (l15*49+quad)%8 uniform -> clean b128
constexpr int W2P = 168;   // W2 LDS row stride: (l15*21+quad)%8 uniform
constexpr int W3P = 136;   // W3 LDS row stride: (l15*17+quad)%8 uniform
constexpr int NMAX = 200000;

using half8  = __attribute__((ext_vector_type(8))) _Float16;
using half4v = __attribute__((ext_vector_type(4))) _Float16;
using f32x4  = __attribute__((ext_vector_type(4))) float;

// Pre-transposed fp16 weights, [species][neuron][k] (753 KB, L2-resident)
__device__ __align__(16) _Float16 g_w1[NSP * H1N * AEV];
__device__ __align__(16) _Float16 g_w2[NSP * H2N * H1N];
__device__ __align__(16) _Float16 g_w3[NSP * H3N * H2N];
// Inter-kernel H1 activations, [species-major atom][160] fp16 (64 MB)
__device__ __align__(16) _Float16 g_h1[(size_t)NMAX * H1N];

DI float celu_f(float x) {   // celu(x,0.1) = max(x,0)+0.1*(exp(min(x,0)/0.1)-1)
  return fmaxf(x, 0.f) + 0.1f * (exp2f(fminf(x, 0.f) * 14.426950408889634f) - 1.f);
}
DI f32x4 mfma16h(half8 a, half8 b, f32x4 c) {
  return __builtin_amdgcn_mfma_f32_16x16x32_f16(a, b, c, 0, 0, 0);
}
DI half8 cvt8(float4 a, float4 b) {
  half8 t;
  t[0] = (_Float16)a.x; t[1] = (_Float16)a.y; t[2] = (_Float16)a.z; t[3] = (_Float16)a.w;
  t[4] = (_Float16)b.x; t[5] = (_Float16)b.y; t[6] = (_Float16)b.z; t[7] = (_Float16)b.w;
  return t;
}

// ---------------- prologue: transpose to [s][n][k] fp16, fused for 3 layers ----
template <int K, int N>
DI void tp(const float* __restrict__ src, _Float16* dst, int id) {
  constexpr int per = K * N;
  int s = id / per, r = id % per;
  int n = r / K, k = r % K;
  dst[s * per + n * K + k] = (_Float16)src[s * per + k * N + n];
}

__global__ void prep(const float* __restrict__ W1, const float* __restrict__ W2,
                     const float* __restrict__ W3, float* __restrict__ out) {
  int id = blockIdx.x * 256 + threadIdx.x;
  if (id == 0) out[0] = 0.f;
  constexpr int E1 = NSP * AEV * H1N;
  constexpr int E2 = NSP * H1N * H2N;
  constexpr int E3 = NSP * H2N * H3N;
  if (id < E1)                 tp<AEV, H1N>(W1, g_w1, id);
  else if (id < E1 + E2)       tp<H1N, H2N>(W2, g_w2, id - E1);
  else if (id < E1 + E2 + E3)  tp<H2N, H3N>(W3, g_w3, id - E1 - E2);
}

// ---------------- Kernel 1: layer 1. W1 LDS-resident, 16 waves x 16 atoms ----
__global__ __launch_bounds__(1024, 4) void layer1_k(
    const float* __restrict__ aev, const float* __restrict__ b1,
    const int* __restrict__ i0, const int* __restrict__ i1,
    const int* __restrict__ i2, const int* __restrict__ i3,
    int chunk) {
  __shared__ __align__(16) _Float16 W1s[H1N * W1P];   // 125440 B

  const int tid  = threadIdx.x;
  const int lane = tid & 63, wav = tid >> 6;
  const int l15  = lane & 15, quad = lane >> 4;
  const int s    = blockIdx.y;
  const int* idx = (s == 0) ? i0 : (s == 1) ? i1 : (s == 2) ? i2 : i3;

  // stage W1[s] -> LDS once (61440 halfs = 7680 half8 chunks)
  const _Float16* wsrc = g_w1 + (size_t)s * H1N * AEV;
#pragma unroll
  for (int i = 0; i < 8; ++i) {
    int c = tid + i * 1024;
    if (c < H1N * (AEV / 8)) {
      int n = c / (AEV / 8), kc = c % (AEV / 8);
      *(half8*)(W1s + n * W1P + kc * 8) = *(const half8*)(wsrc + n * AEV + kc * 8);
    }
  }
  __syncthreads();

  const int a = blockIdx.x * 256 + wav * 16 + l15;          // species-local atom
  const bool valid = (a < chunk);
  const int r = idx[valid ? a : (chunk - 1)];
  const float* xr = aev + (size_t)r * AEV + quad * 8;

  f32x4 acc[10];
#pragma unroll
  for (int m = 0; m < 10; ++m)
#pragma unroll
    for (int i = 0; i < 4; ++i) acc[m][i] = 0.f;

  float4 xf0 = *(const float4*)(xr), xf1 = *(const float4*)(xr + 4);
#pragma unroll
  for (int ks = 0; ks < 12; ++ks) {
    half8 bv = cvt8(xf0, xf1);
    if (ks < 11) {                                          // prefetch next 32-k slab
      xf0 = *(const float4*)(xr + (ks + 1) * 32);
      xf1 = *(const float4*)(xr + (ks + 1) * 32 + 4);
    }
#pragma unroll
    for (int mt = 0; mt < 10; ++mt) {
      half8 aw = *(const half8*)(W1s + (mt * 16 + l15) * W1P + ks * 32 + quad * 8);
      acc[mt] = mfma16h(aw, bv, acc[mt]);
    }
  }
  // epilogue: bias+celu, C-layout (col=atom=l15, rows=quad*4+j) -> g_h1[atom][neuron]
  _Float16* hrow = g_h1 + ((size_t)s * chunk + a) * H1N;
#pragma unroll
  for (int mt = 0; mt < 10; ++mt) {
    float4 bb = *(const float4*)(b1 + s * H1N + mt * 16 + quad * 4);
    half4v o;
    o[0] = (_Float16)celu_f(acc[mt][0] + bb.x);
    o[1] = (_Float16)celu_f(acc[mt][1] + bb.y);
    o[2] = (_Float16)celu_f(acc[mt][2] + bb.z);
    o[3] = (_Float16)celu_f(acc[mt][3] + bb.w);
    if (valid) *(half4v*)(hrow + mt * 16 + quad * 4) = o;
  }
}

// ---------------- Kernel 2: layers 2-4. W2+W3 LDS-resident, per-wave H2 slice ----
__global__ __launch_bounds__(1024, 4) void layer234_k(
    const float* __restrict__ b2, const float* __restrict__ b3,
    const float* __restrict__ W4, const float* __restrict__ pb4,
    int chunk, float* __restrict__ out) {
  __shared__ __align__(16) _Float16 W2s[H2N * W2P];     // 43008 B
  __shared__ __align__(16) _Float16 W3s[H3N * W3P];     // 26112 B
  __shared__ __align__(16) _Float16 H2s[16 * 16 * W3P]; // 16 waves x 16 atoms x 136 = 69632 B
  __shared__ float RED[16];

  const int tid  = threadIdx.x;
  const int lane = tid & 63, wav = tid >> 6;
  const int l15  = lane & 15, quad = lane >> 4;
  const int s    = blockIdx.y;

  const _Float16* w2src = g_w2 + (size_t)s * H2N * H1N;
  const _Float16* w3src = g_w3 + (size_t)s * H3N * H2N;
#pragma unroll
  for (int i = 0; i < 3; ++i) {
    int c = tid + i * 1024;
    if (c < H2N * (H1N / 8)) {
      int n = c / (H1N / 8), kc = c % (H1N / 8);
      *(half8*)(W2s + n * W2P + kc * 8) = *(const half8*)(w2src + n * H1N + kc * 8);
    }
  }
#pragma unroll
  for (int i = 0; i < 2; ++i) {
    int c = tid + i * 1024;
    if (c < H3N * (H2N / 8)) {
      int n = c / (H2N / 8), kc = c % (H2N / 8);
      *(half8*)(W3s + n * W3P + kc * 8) = *(const half8*)(w3src + n * H2N + kc * 8);
    }
  }
  __syncthreads();

  const int a = blockIdx.x * 256 + wav * 16 + l15;
  const bool valid = (a < chunk);
  const int ac = valid ? a : (chunk - 1);
  const _Float16* hrow = g_h1 + ((size_t)s * chunk + ac) * H1N + quad * 8;
  _Float16* H2w = H2s + wav * (16 * W3P);

  // ---- Layer 2: B from g_h1 (issue all 5 slab loads up front)
  half8 bv2[5];
#pragma unroll
  for (int ks = 0; ks < 5; ++ks) bv2[ks] = *(const half8*)(hrow + ks * 32);
  f32x4 acc2[8];
#pragma unroll
  for (int m = 0; m < 8; ++m)
#pragma unroll
    for (int i = 0; i < 4; ++i) acc2[m][i] = 0.f;
#pragma unroll
  for (int mt = 0; mt < 8; ++mt)
#pragma unroll
    for (int ks = 0; ks < 5; ++ks) {
      half8 aw = *(const half8*)(W2s + (mt * 16 + l15) * W2P + ks * 32 + quad * 8);
      acc2[mt] = mfma16h(aw, bv2[ks], acc2[mt]);
    }
#pragma unroll
  for (int mt = 0; mt < 8; ++mt) {
    float4 bb = *(const float4*)(b2 + s * H2N + mt * 16 + quad * 4);
    half4v o;
    o[0] = (_Float16)celu_f(acc2[mt][0] + bb.x);
    o[1] = (_Float16)celu_f(acc2[mt][1] + bb.y);
    o[2] = (_Float16)celu_f(acc2[mt][2] + bb.z);
    o[3] = (_Float16)celu_f(acc2[mt][3] + bb.w);
    *(half4v*)(H2w + l15 * W3P + mt * 16 + quad * 4) = o;   // wave-private, no barrier
  }

  // ---- Layer 3: B from H2w, result back into H2w (reads complete into regs first)
  half8 bv3[4];
#pragma unroll
  for (int ks = 0; ks < 4; ++ks)
    bv3[ks] = *(const half8*)(H2w + l15 * W3P + ks * 32 + quad * 8);
  f32x4 acc3[6];
#pragma unroll
  for (int m = 0; m < 6; ++m)
#pragma unroll
    for (int i = 0; i < 4; ++i) acc3[m][i] = 0.f;
#pragma unroll
  for (int mt = 0; mt < 6; ++mt)
#pragma unroll
    for (int ks = 0; ks < 4; ++ks) {
      half8 aw = *(const half8*)(W3s + (mt * 16 + l15) * W3P + ks * 32 + quad * 8);
      acc3[mt] = mfma16h(aw, bv3[ks], acc3[mt]);
    }
#pragma unroll
  for (int mt = 0; mt < 6; ++mt) {
    float4 bb = *(const float4*)(b3 + s * H3N + mt * 16 + quad * 4);
    half4v o;
    o[0] = (_Float16)celu_f(acc3[mt][0] + bb.x);
    o[1] = (_Float16)celu_f(acc3[mt][1] + bb.y);
    o[2] = (_Float16)celu_f(acc3[mt][2] + bb.z);
    o[3] = (_Float16)celu_f(acc3[mt][3] + bb.w);
    *(half4v*)(H2w + l15 * W3P + mt * 16 + quad * 4) = o;
  }

  // ---- Layer 4: lane (l15=atom, quad=24-elem chunk) dot; reduce; 1 atomic/block
  float e = 0.f;
  {
    const _Float16* h3 = H2w + l15 * W3P + quad * 24;
    const float* w4 = W4 + s * H3N + quad * 24;
#pragma unroll
    for (int j = 0; j < 3; ++j) {
      half8 hv = *(const half8*)(h3 + j * 8);
      float4 wa = *(const float4*)(w4 + j * 8);
      float4 wb = *(const float4*)(w4 + j * 8 + 4);
      e += (float)hv[0] * wa.x + (float)hv[1] * wa.y + (float)hv[2] * wa.z + (float)hv[3] * wa.w
         + (float)hv[4] * wb.x + (float)hv[5] * wb.y + (float)hv[6] * wb.z + (float)hv[7] * wb.w;
    }
  }
  e += __shfl_xor(e, 16, 64);
  e += __shfl_xor(e, 32, 64);            // all lanes with same l15 now hold atom sum
  e = (lane < 16 && valid) ? (e + pb4[s]) : 0.f;
#pragma unroll
  for (int off = 8; off > 0; off >>= 1) e += __shfl_xor(e, off, 64);
  if (lane == 0) RED[wav] = e;
  __syncthreads();
  if (tid == 0) {
    float t = 0.f;
#pragma unroll
    for (int i = 0; i < 16; ++i) t += RED[i];
    atomicAdd(out, t);
  }
}

extern "C" void kernel_launch(void* const* d_in, const int* in_sizes, int n_in,
                              void* d_out, int out_size, void* d_ws, size_t ws_size,
                              hipStream_t stream) {
  (void)n_in; (void)d_ws; (void)ws_size; (void)out_size;
  const float* aev = (const float*)d_in[0];
  const float* W1  = (const float*)d_in[1];
  const float* b1  = (const float*)d_in[2];
  const float* W2  = (const float*)d_in[3];
  const float* b2  = (const float*)d_in[4];
  const float* W3  = (const float*)d_in[5];
  const float* b3  = (const float*)d_in[6];
  const float* W4  = (const float*)d_in[7];
  const float* b4  = (const float*)d_in[8];
  const int* iH = (const int*)d_in[9];
  const int* iC = (const int*)d_in[10];
  const int* iN = (const int*)d_in[11];
  const int* iO = (const int*)d_in[12];
  const int chunk = in_sizes[9];

  constexpr int TOT = NSP * (AEV * H1N + H1N * H2N + H2N * H3N);  // 376832 = 1472*256
  prep<<<TOT / 256, 256, 0, stream>>>(W1, W2, W3, (float*)d_out);

  const int tiles = (chunk + 255) / 256;
  layer1_k<<<dim3(tiles, NSP), 1024, 0, stream>>>(aev, b1, iH, iC, iN, iO, chunk);
  layer234_k<<<dim3(tiles, NSP), 1024, 0, stream>>>(b2, b3, W4, b4, chunk, (float*)d_out);
}

// Round 5
// 478.147 us; speedup vs baseline: 1.4801x; 1.0709x over previous
//
#include <hip/hip_runtime.h>

#define DI __device__ __forceinline__

constexpr int AEV = 384;
constexpr int H1N = 160;
constexpr int H2N = 128;
constexpr int H3N = 96;
constexpr int NSP = 4;
constexpr int W1P = 200;   // W1 K-half LDS row stride (halfs): 100 words, l15*100%32=l15*4 -> 2-way (free)
constexpr int W2P = 168;   // W2 LDS row stride: 84 words, l15*20%32 -> 2-way
constexpr int W3P = 136;   // W3 LDS row stride: 68 words, l15*4%32  -> 2-way
constexpr int W3OFF = H2N * W2P;            // 21504 halfs; W2+W3 = 34560 halfs = 69120 B

using half8  = __attribute__((ext_vector_type(8))) _Float16;
using half4v = __attribute__((ext_vector_type(4))) _Float16;
using f32x4  = __attribute__((ext_vector_type(4))) float;

// Pre-transposed fp16 weights, [species][neuron][k] (753 KB, L2-resident)
__device__ __align__(16) _Float16 g_w1[NSP * H1N * AEV];
__device__ __align__(16) _Float16 g_w2[NSP * H2N * H1N];
__device__ __align__(16) _Float16 g_w3[NSP * H3N * H2N];

DI float celu_f(float x) {   // celu(x,0.1) = max(x,0)+0.1*(exp(min(x,0)/0.1)-1)
  return fmaxf(x, 0.f) + 0.1f * (exp2f(fminf(x, 0.f) * 14.426950408889634f) - 1.f);
}
DI f32x4 mfma16h(half8 a, half8 b, f32x4 c) {
  return __builtin_amdgcn_mfma_f32_16x16x32_f16(a, b, c, 0, 0, 0);
}
DI half8 cvt8(float4 a, float4 b) {
  half8 t;
  t[0] = (_Float16)a.x; t[1] = (_Float16)a.y; t[2] = (_Float16)a.z; t[3] = (_Float16)a.w;
  t[4] = (_Float16)b.x; t[5] = (_Float16)b.y; t[6] = (_Float16)b.z; t[7] = (_Float16)b.w;
  return t;
}
DI half4v shfl4(half4v v, int src) {
  union { half4v h; int i[2]; } u;
  u.h = v;
  u.i[0] = __shfl(u.i[0], src, 64);
  u.i[1] = __shfl(u.i[1], src, 64);
  return u.h;
}
// Build B-fragment slab ks for next layer from C-layout regs hb[]:
// dest lane (l15=atom, quad) needs H[k=ks*32+quad*8+j][atom], living in
// hb[2ks+(quad>>1)] of lanes ((quad&1)*32 + l15) [lo] and (+16) [hi].
// shfl transmits the SOURCE lane's value, so pull both mt candidates and select.
DI half8 bfrag(const half4v* hb, int ks, int l15, int quad) {
  const int sLo = (quad & 1) * 32 + l15, sHi = sLo + 16;
  half4v loA = shfl4(hb[2 * ks], sLo),     loB = shfl4(hb[2 * ks + 1], sLo);
  half4v hiA = shfl4(hb[2 * ks], sHi),     hiB = shfl4(hb[2 * ks + 1], sHi);
  half4v lo = (quad & 2) ? loB : loA;
  half4v hi = (quad & 2) ? hiB : hiA;
  half8 b;
  b[0] = lo[0]; b[1] = lo[1]; b[2] = lo[2]; b[3] = lo[3];
  b[4] = hi[0]; b[5] = hi[1]; b[6] = hi[2]; b[7] = hi[3];
  return b;
}

// ---------------- prologue: transpose to [s][n][k] fp16, fused for 3 layers ----
template <int K, int N>
DI void tp(const float* __restrict__ src, _Float16* dst, int id) {
  constexpr int per = K * N;
  int s = id / per, r = id % per;
  int n = r / K, k = r % K;
  dst[s * per + n * K + k] = (_Float16)src[s * per + k * N + n];
}

__global__ void prep(const float* __restrict__ W1, const float* __restrict__ W2,
                     const float* __restrict__ W3, float* __restrict__ out) {
  int id = blockIdx.x * 256 + threadIdx.x;
  if (id == 0) out[0] = 0.f;
  constexpr int E1 = NSP * AEV * H1N;
  constexpr int E2 = NSP * H1N * H2N;
  constexpr int E3 = NSP * H2N * H3N;
  if (id < E1)                 tp<AEV, H1N>(W1, g_w1, id);
  else if (id < E1 + E2)       tp<H1N, H2N>(W2, g_w2, id - E1);
  else if (id < E1 + E2 + E3)  tp<H2N, H3N>(W3, g_w3, id - E1 - E2);
}

// ---------------- fused MLP: all activations in registers; LDS = weights only ----
__global__ __launch_bounds__(512, 4) void fused_mlp(
    const float* __restrict__ aev,
    const float* __restrict__ b1, const float* __restrict__ b2,
    const float* __restrict__ b3,
    const float* __restrict__ W4, const float* __restrict__ pb4,
    const int* __restrict__ i0, const int* __restrict__ i1,
    const int* __restrict__ i2, const int* __restrict__ i3,
    int chunk, float* __restrict__ out) {
  __shared__ __align__(16) _Float16 WS[34560];   // 69120 B: W1-half | later W2+W3
  __shared__ float RED[8];

  const int tid  = threadIdx.x;
  const int lane = tid & 63, wav = tid >> 6;
  const int l15  = lane & 15, quad = lane >> 4;
  const int s    = blockIdx.y;
  const int* idx = (s == 0) ? i0 : (s == 1) ? i1 : (s == 2) ? i2 : i3;

  const int a = blockIdx.x * 128 + wav * 16 + l15;     // species-local atom
  const bool valid = (a < chunk);
  const int r = idx[valid ? a : (chunk - 1)];
  const float* xr = aev + (size_t)r * AEV + quad * 8;

  const _Float16* w1src = g_w1 + (size_t)s * H1N * AEV;

  // ---- stage W1 K-half 0 (k=0..191), stride W1P
#pragma unroll
  for (int i = 0; i < 8; ++i) {
    int c = tid + i * 512;
    if (c < H1N * 24) {
      int n = c / 24, kc = c % 24;
      *(half8*)(WS + n * W1P + kc * 8) = *(const half8*)(w1src + n * AEV + kc * 8);
    }
  }
  __syncthreads();

  // ---- Layer 1 (K=384 split 2x192), aev slab prefetch keeps HBM busy across barriers
  f32x4 acc[10];
#pragma unroll
  for (int m = 0; m < 10; ++m)
#pragma unroll
    for (int i = 0; i < 4; ++i) acc[m][i] = 0.f;

  float4 xf0 = *(const float4*)(xr), xf1 = *(const float4*)(xr + 4);
#pragma unroll
  for (int ks = 0; ks < 6; ++ks) {
    half8 bv = cvt8(xf0, xf1);
    xf0 = *(const float4*)(xr + (ks + 1) * 32);       // prefetch (ks=5 pulls A2's first slab)
    xf1 = *(const float4*)(xr + (ks + 1) * 32 + 4);
#pragma unroll
    for (int mt = 0; mt < 10; ++mt) {
      half8 aw = *(const half8*)(WS + (mt * 16 + l15) * W1P + ks * 32 + quad * 8);
      acc[mt] = mfma16h(aw, bv, acc[mt]);
    }
  }
  __syncthreads();                                     // done reading half 0
#pragma unroll
  for (int i = 0; i < 8; ++i) {                        // stage K-half 1 (k=192..383)
    int c = tid + i * 512;
    if (c < H1N * 24) {
      int n = c / 24, kc = c % 24;
      *(half8*)(WS + n * W1P + kc * 8) = *(const half8*)(w1src + 192 + n * AEV + kc * 8);
    }
  }
  __syncthreads();
#pragma unroll
  for (int ks = 6; ks < 12; ++ks) {
    half8 bv = cvt8(xf0, xf1);
    if (ks < 11) {
      xf0 = *(const float4*)(xr + (ks + 1) * 32);
      xf1 = *(const float4*)(xr + (ks + 1) * 32 + 4);
    }
#pragma unroll
    for (int mt = 0; mt < 10; ++mt) {
      half8 aw = *(const half8*)(WS + (mt * 16 + l15) * W1P + (ks - 6) * 32 + quad * 8);
      acc[mt] = mfma16h(aw, bv, acc[mt]);
    }
  }
  // epilogue in regs: hb[mt][i] = H1[n=mt*16+quad*4+i][atom=l15]
  half4v hb[10];
#pragma unroll
  for (int mt = 0; mt < 10; ++mt) {
    float4 bb = *(const float4*)(b1 + s * H1N + mt * 16 + quad * 4);
    half4v o;
    o[0] = (_Float16)celu_f(acc[mt][0] + bb.x);
    o[1] = (_Float16)celu_f(acc[mt][1] + bb.y);
    o[2] = (_Float16)celu_f(acc[mt][2] + bb.z);
    o[3] = (_Float16)celu_f(acc[mt][3] + bb.w);
    hb[mt] = o;
  }

  __syncthreads();                                     // done reading W1 half 1
  {                                                    // stage W2 (stride W2P) + W3 (stride W3P)
    const _Float16* w2src = g_w2 + (size_t)s * H2N * H1N;
    const _Float16* w3src = g_w3 + (size_t)s * H3N * H2N;
#pragma unroll
    for (int i = 0; i < 5; ++i) {
      int c = tid + i * 512;                           // 128*20 = 2560 exact
      int n = c / 20, kc = c % 20;
      *(half8*)(WS + n * W2P + kc * 8) = *(const half8*)(w2src + n * H1N + kc * 8);
    }
#pragma unroll
    for (int i = 0; i < 3; ++i) {
      int c = tid + i * 512;                           // 96*16 = 1536 exact
      int n = c / 16, kc = c % 16;
      *(half8*)(WS + W3OFF + n * W3P + kc * 8) = *(const half8*)(w3src + n * H2N + kc * 8);
    }
  }
  __syncthreads();

  // ---- Layer 2 (K=160): B-frags via shfl from hb
  f32x4 acc2[8];
#pragma unroll
  for (int m = 0; m < 8; ++m)
#pragma unroll
    for (int i = 0; i < 4; ++i) acc2[m][i] = 0.f;
#pragma unroll
  for (int ks = 0; ks < 5; ++ks) {
    half8 bv = bfrag(hb, ks, l15, quad);
#pragma unroll
    for (int mt = 0; mt < 8; ++mt) {
      half8 aw = *(const half8*)(WS + (mt * 16 + l15) * W2P + ks * 32 + quad * 8);
      acc2[mt] = mfma16h(aw, bv, acc2[mt]);
    }
  }
  half4v hb2[8];
#pragma unroll
  for (int mt = 0; mt < 8; ++mt) {
    float4 bb = *(const float4*)(b2 + s * H2N + mt * 16 + quad * 4);
    half4v o;
    o[0] = (_Float16)celu_f(acc2[mt][0] + bb.x);
    o[1] = (_Float16)celu_f(acc2[mt][1] + bb.y);
    o[2] = (_Float16)celu_f(acc2[mt][2] + bb.z);
    o[3] = (_Float16)celu_f(acc2[mt][3] + bb.w);
    hb2[mt] = o;
  }

  // ---- Layer 3 (K=128)
  f32x4 acc3[6];
#pragma unroll
  for (int m = 0; m < 6; ++m)
#pragma unroll
    for (int i = 0; i < 4; ++i) acc3[m][i] = 0.f;
#pragma unroll
  for (int ks = 0; ks < 4; ++ks) {
    half8 bv = bfrag(hb2, ks, l15, quad);
#pragma unroll
    for (int mt = 0; mt < 6; ++mt) {
      half8 aw = *(const half8*)(WS + W3OFF + (mt * 16 + l15) * W3P + ks * 32 + quad * 8);
      acc3[mt] = mfma16h(aw, bv, acc3[mt]);
    }
  }

  // ---- Layer 4: per-lane partial dot over its (quad,i) neurons, then lane reduce
  float e = 0.f;
#pragma unroll
  for (int mt = 0; mt < 6; ++mt) {
    float4 bb = *(const float4*)(b3 + s * H3N + mt * 16 + quad * 4);
    float4 wv = *(const float4*)(W4 + s * H3N + mt * 16 + quad * 4);
    e += (float)(_Float16)celu_f(acc3[mt][0] + bb.x) * wv.x
       + (float)(_Float16)celu_f(acc3[mt][1] + bb.y) * wv.y
       + (float)(_Float16)celu_f(acc3[mt][2] + bb.z) * wv.z
       + (float)(_Float16)celu_f(acc3[mt][3] + bb.w) * wv.w;
  }
  e += __shfl_xor(e, 16, 64);
  e += __shfl_xor(e, 32, 64);              // lanes sharing l15 now hold the atom's dot
  e = (lane < 16 && valid) ? (e + pb4[s]) : 0.f;
#pragma unroll
  for (int off = 1; off < 64; off <<= 1) e += __shfl_xor(e, off, 64);
  if (lane == 0) RED[wav] = e;
  __syncthreads();
  if (tid == 0) {
    float t = 0.f;
#pragma unroll
    for (int i = 0; i < 8; ++i) t += RED[i];
    atomicAdd(out, t);
  }
}

extern "C" void kernel_launch(void* const* d_in, const int* in_sizes, int n_in,
                              void* d_out, int out_size, void* d_ws, size_t ws_size,
                              hipStream_t stream) {
  (void)n_in; (void)d_ws; (void)ws_size; (void)out_size;
  const float* aev = (const float*)d_in[0];
  const float* W1  = (const float*)d_in[1];
  const float* b1  = (const float*)d_in[2];
  const float* W2  = (const float*)d_in[3];
  const float* b2  = (const float*)d_in[4];
  const float* W3  = (const float*)d_in[5];
  const float* b3  = (const float*)d_in[6];
  const float* W4  = (const float*)d_in[7];
  const float* b4  = (const float*)d_in[8];
  const int* iH = (const int*)d_in[9];
  const int* iC = (const int*)d_in[10];
  const int* iN = (const int*)d_in[11];
  const int* iO = (const int*)d_in[12];
  const int chunk = in_sizes[9];

  constexpr int TOT = NSP * (AEV * H1N + H1N * H2N + H2N * H3N);  // 376832 = 1472*256
  prep<<<TOT / 256, 256, 0, stream>>>(W1, W2, W3, (float*)d_out);

  const int tiles = (chunk + 127) / 128;
  fused_mlp<<<dim3(tiles, NSP), 512, 0, stream>>>(aev, b1, b2, b3, W4, b4,
                                                  iH, iC, iN, iO, chunk, (float*)d_out);
}